// Round 9
// baseline (1956.086 us; speedup 1.0000x reference)
//
#include <hip/hip_runtime.h>
#include <cstdint>

constexpr int N_NODES = 5461;

using f16x8 = __attribute__((ext_vector_type(8))) _Float16;
using f32x4 = __attribute__((ext_vector_type(4))) float;

typedef const __attribute__((address_space(1))) unsigned int* gas_p;
typedef __attribute__((address_space(3))) unsigned int* las_p;

__device__ __forceinline__ float sigm(float v) { return 1.0f / (1.0f + __expf(-v)); }

__constant__ int d_STARTS[8] = {0, 1, 5, 21, 85, 341, 1365, 5461};

// ---------------- split-fp16 MFMA GEMM tile (device body; verified r8) ----------------
// 512 threads = 8 waves (2M x 4N), wave tile 64x32, block tile 128x128, K=512, 16 steps.
// LDS chunk-XOR swizzle: row r's 16B chunk c at slot c^((r>>1)&3); staged via
// inverse-permuted GLOBAL source (LDS dest linear); read slot kg^((rsel>>1)&3). 0 conflicts.
struct GSet {
    const _Float16 *Ah, *Al;
    const _Float16 *BhL, *BlL, *BhV, *BlV;
    const float *biasL, *biasV;
    float* Y;
    const int* permA;      // null => identity
    int nL, M, Nout;       // nL filled at runtime from cnt
};

__device__ void gemm_tile(const GSet& S, int tx, int bn)
{
    const int nTl = (S.nL + 127) >> 7;
    int rowBase, rowEnd;
    const _Float16 *Bh, *Bl;
    const float* bias;
    if (tx < nTl) {
        rowBase = tx << 7; rowEnd = S.nL;
        Bh = S.BhL; Bl = S.BlL; bias = S.biasL;
    } else {
        rowBase = S.nL + ((tx - nTl) << 7); rowEnd = S.M;
        Bh = S.BhV; Bl = S.BlV; bias = S.biasV;
    }
    if (rowBase >= rowEnd) return;

    __shared__ _Float16 AsH[2][128 * 32];
    __shared__ _Float16 AsL[2][128 * 32];
    __shared__ _Float16 BsH[2][128 * 32];
    __shared__ _Float16 BsL[2][128 * 32];

    const int tid = threadIdx.x;
    const int wid = tid >> 6;          // 0..7
    const int lane = tid & 63;
    const int wm = (wid >> 2) * 64;
    const int wn = (wid & 3) * 32;
    const int rsel = lane & 15;
    const int kg = lane >> 4;
    const int lrow = lane >> 2;
    const int csrc = ((lane & 3) ^ ((lane >> 3) & 3)) * 8;
    int aR = rowBase + wid * 16 + lrow; if (aR > rowEnd - 1) aR = rowEnd - 1;
    const int a0 = S.permA ? S.permA[aR] : aR;
    const _Float16* gAh = S.Ah + (size_t)a0 * 512 + csrc;
    const _Float16* gAl = S.Al + (size_t)a0 * 512 + csrc;
    const _Float16* gBh = Bh + (size_t)(bn + wid * 16 + lrow) * 512 + csrc;
    const _Float16* gBl = Bl + (size_t)(bn + wid * 16 + lrow) * 512 + csrc;

    f32x4 acc0[4][2] = {};
    f32x4 acc1[4][2] = {};

    auto stage = [&](int k0, int b) {
        __builtin_amdgcn_global_load_lds((gas_p)(const void*)(gAh + k0), (las_p)(void*)(&AsH[b][wid * 512]), 16, 0, 0);
        __builtin_amdgcn_global_load_lds((gas_p)(const void*)(gAl + k0), (las_p)(void*)(&AsL[b][wid * 512]), 16, 0, 0);
        __builtin_amdgcn_global_load_lds((gas_p)(const void*)(gBh + k0), (las_p)(void*)(&BsH[b][wid * 512]), 16, 0, 0);
        __builtin_amdgcn_global_load_lds((gas_p)(const void*)(gBl + k0), (las_p)(void*)(&BsL[b][wid * 512]), 16, 0, 0);
    };

    const int sl = kg ^ ((rsel >> 1) & 3);

    stage(0, 0);
    __syncthreads();
#pragma unroll 1
    for (int step = 0; step < 16; ++step) {
        const int cur = step & 1;
        if (step < 15) stage((step + 1) * 32, cur ^ 1);
        const f16x8* AH = (const f16x8*)AsH[cur];
        const f16x8* AL = (const f16x8*)AsL[cur];
        const f16x8* BH = (const f16x8*)BsH[cur];
        const f16x8* BL = (const f16x8*)BsL[cur];
        f16x8 bh[2], bl[2];
#pragma unroll
        for (int j = 0; j < 2; ++j) {
            int bi = (wn + j * 16 + rsel) * 4 + sl;
            bh[j] = BH[bi];
            bl[j] = BL[bi];
        }
#pragma unroll
        for (int i = 0; i < 4; ++i) {
            int ai = (wm + i * 16 + rsel) * 4 + sl;
            f16x8 ah = AH[ai];
            f16x8 al = AL[ai];
#pragma unroll
            for (int j = 0; j < 2; ++j) {
                acc0[i][j] = __builtin_amdgcn_mfma_f32_16x16x32_f16(ah, bh[j], acc0[i][j], 0, 0, 0);
                acc1[i][j] = __builtin_amdgcn_mfma_f32_16x16x32_f16(ah, bl[j], acc1[i][j], 0, 0, 0);
                acc1[i][j] = __builtin_amdgcn_mfma_f32_16x16x32_f16(al, bh[j], acc1[i][j], 0, 0, 0);
            }
        }
        __syncthreads();
    }

    // C/D layout: col=lane&15, row=(lane>>4)*4+reg  [HW-verified]
#pragma unroll
    for (int i = 0; i < 4; ++i) {
        int row0 = rowBase + wm + i * 16 + kg * 4;
#pragma unroll
        for (int j = 0; j < 2; ++j) {
            int col = bn + wn + j * 16 + rsel;
            float bb = bias[col];
#pragma unroll
            for (int r = 0; r < 4; ++r) {
                int row = row0 + r;
                if (row < rowEnd)
                    S.Y[(size_t)row * S.Nout + col] = acc0[i][j][r] + acc1[i][j][r] * (1.0f / 2048.0f) + bb;
            }
        }
    }
}

// ---------------- device-wide barrier: per-phase counter (memset to 0 each launch) ----------------
__device__ __forceinline__ void gbar(int* c, int nb)
{
    __syncthreads();
    if (threadIdx.x == 0) {
        __threadfence();
        __hip_atomic_fetch_add(c, 1, __ATOMIC_ACQ_REL, __HIP_MEMORY_SCOPE_AGENT);
        while (__hip_atomic_load(c, __ATOMIC_ACQUIRE, __HIP_MEMORY_SCOPE_AGENT) < nb)
            __builtin_amdgcn_s_sleep(2);
    }
    __syncthreads();
}

// ---------------- mega kernel: precompute GEMM + full tree tail, one launch ----------------
struct Mega {
    GSet pre0, pre1;     // x @ W_ioux / W_fx (permA = perm_g)
    GSet lv0, lv1;       // hs @ W_iouh / ch @ W_fh (per-level M filled in kernel)
    const int* cnt;      // cnt[0]=global langs, cnt[1+l]=level-l langs
    const float *iou_pre, *fx_pre;
    float *iou_h, *fpre, *c_all, *h_all;
    const int *children, *lvlPerm, *lvlInv, *inv_g;
    const float *b_iouh_v, *b_iouh_l;
    _Float16 *hs_h, *hs_l, *ch_h, *ch_l;
    int* sync;
};

__device__ void leaf_body(const Mega& m, int w, int t)
{
    const int ip = w;                           // 0..1023 level-5 parent slots
    const int p = m.lvlPerm[341 + ip];
    const int d0 = t * 2;
    const int nLg = m.cnt[0];
    float hsum[2] = {0.f, 0.f};
#pragma unroll
    for (int k = 0; k < 4; ++k) {
        int cnode = m.children[p * 4 + k];
        int u = m.inv_g[cnode];
        const float* bh = (u < nLg) ? m.b_iouh_l : m.b_iouh_v;
        size_t ub = (size_t)u * 1536;
#pragma unroll
        for (int e = 0; e < 2; ++e) {
            int d = d0 + e;
            float iv = m.iou_pre[ub + d]        + bh[d];
            float ov = m.iou_pre[ub + 512 + d]  + bh[512 + d];
            float uv = m.iou_pre[ub + 1024 + d] + bh[1024 + d];
            float cc = sigm(iv) * tanhf(uv);
            float hh = sigm(ov) * tanhf(cc);
            m.c_all[(size_t)cnode * 512 + d] = cc;
            m.h_all[(size_t)cnode * 512 + d] = hh;
            hsum[e] += hh;
            _Float16 hf = (_Float16)hh;
            size_t o = ((size_t)(ip * 4 + k)) * 512 + d;
            m.ch_h[o] = hf;
            m.ch_l[o] = (_Float16)((hh - (float)hf) * 2048.0f);
        }
    }
#pragma unroll
    for (int e = 0; e < 2; ++e) {
        _Float16 sh = (_Float16)hsum[e];
        m.hs_h[(size_t)ip * 512 + d0 + e] = sh;
        m.hs_l[(size_t)ip * 512 + d0 + e] = (_Float16)((hsum[e] - (float)sh) * 2048.0f);
    }
}

__device__ void combine_body(const Mega& m, int l, int w, int t)
{
    const int sPar = d_STARTS[l - 1];
    const int sLvl = d_STARTS[l];
    const int nPar = sLvl - sPar;
    const int d0 = t * 2;
    for (int ip = w; ip < nPar; ip += 1024) {
        int p = m.lvlPerm[sPar + ip];
        float hsum[2] = {0.f, 0.f};
#pragma unroll
        for (int k = 0; k < 4; ++k) {
            int cnode = m.children[p * 4 + k];
            int j = m.lvlInv[cnode] - sLvl;
            int u = m.inv_g[cnode];
            size_t ub = (size_t)u * 1536;
            size_t jb = (size_t)j * 1536;
#pragma unroll
            for (int e = 0; e < 2; ++e) {
                int d = d0 + e;
                float iv = m.iou_pre[ub + d]        + m.iou_h[jb + d];
                float ov = m.iou_pre[ub + 512 + d]  + m.iou_h[jb + 512 + d];
                float uv = m.iou_pre[ub + 1024 + d] + m.iou_h[jb + 1024 + d];
                float fxn = m.fx_pre[(size_t)u * 512 + d];
                float csum = 0.f;
#pragma unroll
                for (int k2 = 0; k2 < 4; ++k2) {
                    int gc = m.children[cnode * 4 + k2];
                    float f = sigm(m.fpre[((size_t)(j * 4 + k2)) * 512 + d] + fxn);
                    csum = fmaf(f, m.c_all[(size_t)gc * 512 + d], csum);
                }
                float cc = sigm(iv) * tanhf(uv) + csum;
                float hh = sigm(ov) * tanhf(cc);
                m.c_all[(size_t)cnode * 512 + d] = cc;
                m.h_all[(size_t)cnode * 512 + d] = hh;
                hsum[e] += hh;
                _Float16 hf = (_Float16)hh;
                size_t o = ((size_t)(ip * 4 + k)) * 512 + d;
                m.ch_h[o] = hf;
                m.ch_l[o] = (_Float16)((hh - (float)hf) * 2048.0f);
            }
        }
#pragma unroll
        for (int e = 0; e < 2; ++e) {
            _Float16 sh = (_Float16)hsum[e];
            m.hs_h[(size_t)ip * 512 + d0 + e] = sh;
            m.hs_l[(size_t)ip * 512 + d0 + e] = (_Float16)((hsum[e] - (float)sh) * 2048.0f);
        }
    }
}

__device__ void root_body(const Mega& m, int w, int t)
{
    if (w >= 2) return;
    int d = w * 256 + t;
    int u = m.inv_g[0];
    size_t ub = (size_t)u * 1536;
    float iv = m.iou_pre[ub + d]        + m.iou_h[d];
    float ov = m.iou_pre[ub + 512 + d]  + m.iou_h[512 + d];
    float uv = m.iou_pre[ub + 1024 + d] + m.iou_h[1024 + d];
    float fxn = m.fx_pre[(size_t)u * 512 + d];
    float csum = 0.f;
#pragma unroll
    for (int k = 0; k < 4; ++k) {
        int gc = m.children[k];
        float f = sigm(m.fpre[(size_t)k * 512 + d] + fxn);
        csum = fmaf(f, m.c_all[(size_t)gc * 512 + d], csum);
    }
    float cc = sigm(iv) * tanhf(uv) + csum;
    float hh = sigm(ov) * tanhf(cc);
    m.c_all[d] = cc;
    m.h_all[d] = hh;
}

__device__ void level_gemm(const Mega& m, int l, int nb)
{
    const int E = d_STARTS[l + 1] - d_STARTS[l];
    const int langs = m.cnt[1 + l];
    GSet s0 = m.lv0; s0.nL = langs;     s0.M = E;
    GSet s1 = m.lv1; s1.nL = langs * 4; s1.M = E * 4;
    const int gx = (E * 4 + 127) / 128 + 1;
    for (int f = blockIdx.x; f < gx * 16; f += nb) {
        int ty = f & 15, tx = f >> 4;
        if (ty < 12) gemm_tile(s0, tx, ty * 128);
        else         gemm_tile(s1, tx, (ty - 12) * 128);
    }
}

__global__ __launch_bounds__(512, 4)
void mega(Mega m)
{
    const int nb = gridDim.x;
    const int w = blockIdx.x * 2 + (threadIdx.x >> 8);
    const int t = threadIdx.x & 255;

    // ---- phase 0: precompute GEMMs (ioux 12 col-tiles + fx 4 col-tiles) ----
    {
        GSet s0 = m.pre0; s0.nL = m.cnt[0];
        GSet s1 = m.pre1; s1.nL = m.cnt[0];
        const int gx = (N_NODES + 127) / 128 + 1;   // 44
        for (int f = blockIdx.x; f < gx * 16; f += nb) {
            int ty = f & 15, tx = f >> 4;
            if (ty < 12) gemm_tile(s0, tx, ty * 128);
            else         gemm_tile(s1, tx, (ty - 12) * 128);
        }
    }
    gbar(m.sync + 0, nb);

    // ---- phase 1: leaves + gather(level 5) ----
    leaf_body(m, w, t);
    gbar(m.sync + 1, nb);

    int ph = 2;
#pragma unroll 1
    for (int l = 5; l >= 1; --l) {
        level_gemm(m, l, nb);
        gbar(m.sync + ph, nb); ++ph;
        combine_body(m, l, w, t);
        gbar(m.sync + ph, nb); ++ph;
    }
    level_gemm(m, 0, nb);
    gbar(m.sync + 12, nb);
    root_body(m, w, t);
}

// ---------------- fused: x -> fp16 hi/lo split + type-selector logits ----------------
__global__ __launch_bounds__(256)
void cast_x_sel(const float* __restrict__ x, const float* __restrict__ Wt,
                const float* __restrict__ bt,
                _Float16* __restrict__ hi, _Float16* __restrict__ lo,
                int* __restrict__ sel)
{
    __shared__ float s0[256], s1[256];
    int t = threadIdx.x;
    int row = blockIdx.x * 2 + (t >> 7);
    int c0 = (t & 127) * 4;
    float p0 = 0.f, p1 = 0.f;
    if (row < N_NODES) {
        size_t off = (size_t)row * 512 + c0;
        float4 v = *(const float4*)(x + off);
        float vv[4] = {v.x, v.y, v.z, v.w};
        union { _Float16 h[4]; ushort4 u; } H, L;
#pragma unroll
        for (int i = 0; i < 4; ++i) {
            _Float16 h = (_Float16)vv[i];
            H.h[i] = h;
            L.h[i] = (_Float16)((vv[i] - (float)h) * 2048.0f);
            p0 = fmaf(vv[i], Wt[(c0 + i) * 2], p0);
            p1 = fmaf(vv[i], Wt[(c0 + i) * 2 + 1], p1);
        }
        *(ushort4*)(hi + off) = H.u;
        *(ushort4*)(lo + off) = L.u;
    }
    s0[t] = p0; s1[t] = p1;
    __syncthreads();
    for (int st = 64; st > 0; st >>= 1) {
        if ((t & 127) < st) { s0[t] += s0[t + st]; s1[t] += s1[t + st]; }
        __syncthreads();
    }
    if ((t & 127) == 0 && row < N_NODES)
        sel[row] = (s0[t] + bt[0] >= s1[t] + bt[1]) ? 1 : 0;
}

// ---------------- prep: transpose+split-cast weights (blocks 0..1535) | partition (1536..1542) ----------------
struct WtArgs {
    const float* src[8];
    _Float16* dsth[8];
    _Float16* dstl[8];
    int nout[8];
};

__global__ __launch_bounds__(256)
void prep(WtArgs a, const int* __restrict__ sel, int* __restrict__ perm_g,
          int* __restrict__ inv_g, int* __restrict__ lvlPerm,
          int* __restrict__ lvlInv, int* __restrict__ cnt)
{
    if (blockIdx.x < 1536) {
        int idx = blockIdx.x;
        int mi = idx / 192;
        int r = idx % 192;
        int n0 = (r >> 3) * 64;
        int k0 = (r & 7) * 64;
        int Nout = a.nout[mi];
        if (n0 >= Nout) return;
        const float* W = a.src[mi];
        _Float16* TH = a.dsth[mi];
        _Float16* TL = a.dstl[mi];
        __shared__ float tbuf[64][65];
        int tx = threadIdx.x & 63, ty = threadIdx.x >> 6;
#pragma unroll
        for (int rr = ty; rr < 64; rr += 4)
            tbuf[rr][tx] = W[(size_t)(k0 + rr) * Nout + n0 + tx];
        __syncthreads();
#pragma unroll
        for (int rr = ty; rr < 64; rr += 4) {
            float v = tbuf[tx][rr];
            _Float16 h = (_Float16)v;
            TH[(size_t)(n0 + rr) * 512 + k0 + tx] = h;
            TL[(size_t)(n0 + rr) * 512 + k0 + tx] = (_Float16)((v - (float)h) * 2048.0f);
        }
    } else {
        __shared__ int ps[256];
        int b = blockIdx.x - 1536;        // 0..6
        int s, e;
        if (b == 0) { s = 0; e = N_NODES; }
        else { s = d_STARTS[b - 1]; e = d_STARTS[b]; }
        int E = e - s;
        int t = threadIdx.x;
        int chunk = (E + 255) / 256;
        int beg = min(t * chunk, E);
        int end = min(beg + chunk, E);
        int c = 0;
        for (int i = beg; i < end; ++i) c += sel[s + i];
        ps[t] = c;
        __syncthreads();
        for (int off = 1; off < 256; off <<= 1) {
            int other = (t >= off) ? ps[t - off] : 0;
            __syncthreads();
            ps[t] += other;
            __syncthreads();
        }
        int total = ps[255];
        int excl = ps[t] - c;
        int pL = excl;
        int pV = total + (beg - excl);
        for (int i = beg; i < end; ++i) {
            int node = s + i;
            int pos = sel[node] ? pL++ : pV++;
            int slot = s + pos;
            if (b == 0) { perm_g[slot] = node; inv_g[node] = slot; }
            else { lvlPerm[slot] = node; lvlInv[node] = slot; }
        }
        if (t == 0) cnt[b] = total;
    }
}

extern "C" void kernel_launch(void* const* d_in, const int* in_sizes, int n_in,
                              void* d_out, int out_size, void* d_ws, size_t ws_size,
                              hipStream_t stream)
{
    const float* x        = (const float*)d_in[0];
    const int*   children = (const int*)  d_in[1];
    const float* W_ioux_v = (const float*)d_in[2];
    const float* b_ioux_v = (const float*)d_in[3];
    const float* W_iouh_v = (const float*)d_in[4];
    const float* b_iouh_v = (const float*)d_in[5];
    const float* W_fx_v   = (const float*)d_in[6];
    const float* b_fx_v   = (const float*)d_in[7];
    const float* W_fh_v   = (const float*)d_in[8];
    const float* b_fh_v   = (const float*)d_in[9];
    const float* W_ioux_l = (const float*)d_in[10];
    const float* b_ioux_l = (const float*)d_in[11];
    const float* W_iouh_l = (const float*)d_in[12];
    const float* b_iouh_l = (const float*)d_in[13];
    const float* W_fx_l   = (const float*)d_in[14];
    const float* b_fx_l   = (const float*)d_in[15];
    const float* W_fh_l   = (const float*)d_in[16];
    const float* b_fh_l   = (const float*)d_in[17];
    const float* W_type   = (const float*)d_in[18];
    const float* b_type   = (const float*)d_in[19];
    float* h_all = (float*)d_out;

    // ---- workspace carve-up ----
    float* p = (float*)d_ws;
    float* iou_pre = p; p += (size_t)N_NODES * 1536;
    float* fx_pre  = p; p += (size_t)N_NODES * 512;
    float* c_all   = p; p += (size_t)N_NODES * 512;
    float* iou_h   = p; p += (size_t)1024 * 1536;
    float* fpre    = p; p += (size_t)4096 * 512;
    int* sel     = (int*)p; p += 6144;
    int* perm_g  = (int*)p; p += 6144;
    int* inv_g   = (int*)p; p += 6144;
    int* lvlPerm = (int*)p; p += 2048;
    int* lvlInv  = (int*)p; p += 2048;
    int* cnt     = (int*)p; p += 64;
    int* gsync   = (int*)p; p += 64;
    _Float16* q = (_Float16*)p;
    _Float16* xh   = q; q += (size_t)N_NODES * 512;
    _Float16* xl   = q; q += (size_t)N_NODES * 512;
    _Float16* hs_h = q; q += (size_t)1024 * 512;
    _Float16* hs_l = q; q += (size_t)1024 * 512;
    _Float16* ch_h = q; q += (size_t)4096 * 512;
    _Float16* ch_l = q; q += (size_t)4096 * 512;
    _Float16* wt_ioux_vh = q; q += (size_t)1536 * 512;
    _Float16* wt_ioux_vl = q; q += (size_t)1536 * 512;
    _Float16* wt_ioux_lh = q; q += (size_t)1536 * 512;
    _Float16* wt_ioux_ll = q; q += (size_t)1536 * 512;
    _Float16* wt_iouh_vh = q; q += (size_t)1536 * 512;
    _Float16* wt_iouh_vl = q; q += (size_t)1536 * 512;
    _Float16* wt_iouh_lh = q; q += (size_t)1536 * 512;
    _Float16* wt_iouh_ll = q; q += (size_t)1536 * 512;
    _Float16* wt_fx_vh   = q; q += (size_t)512 * 512;
    _Float16* wt_fx_vl   = q; q += (size_t)512 * 512;
    _Float16* wt_fx_lh   = q; q += (size_t)512 * 512;
    _Float16* wt_fx_ll   = q; q += (size_t)512 * 512;
    _Float16* wt_fh_vh   = q; q += (size_t)512 * 512;
    _Float16* wt_fh_vl   = q; q += (size_t)512 * 512;
    _Float16* wt_fh_lh   = q; q += (size_t)512 * 512;
    _Float16* wt_fh_ll   = q; q += (size_t)512 * 512;

    // ---- reset barrier counters (captured; runs every replay) ----
    hipMemsetAsync(gsync, 0, 64 * sizeof(int), stream);

    cast_x_sel<<<(N_NODES + 1) / 2, 256, 0, stream>>>(x, W_type, b_type, xh, xl, sel);

    WtArgs wa;
    wa.src[0] = W_ioux_v; wa.dsth[0] = wt_ioux_vh; wa.dstl[0] = wt_ioux_vl; wa.nout[0] = 1536;
    wa.src[1] = W_ioux_l; wa.dsth[1] = wt_ioux_lh; wa.dstl[1] = wt_ioux_ll; wa.nout[1] = 1536;
    wa.src[2] = W_iouh_v; wa.dsth[2] = wt_iouh_vh; wa.dstl[2] = wt_iouh_vl; wa.nout[2] = 1536;
    wa.src[3] = W_iouh_l; wa.dsth[3] = wt_iouh_lh; wa.dstl[3] = wt_iouh_ll; wa.nout[3] = 1536;
    wa.src[4] = W_fx_v;   wa.dsth[4] = wt_fx_vh;   wa.dstl[4] = wt_fx_vl;   wa.nout[4] = 512;
    wa.src[5] = W_fx_l;   wa.dsth[5] = wt_fx_lh;   wa.dstl[5] = wt_fx_ll;   wa.nout[5] = 512;
    wa.src[6] = W_fh_v;   wa.dsth[6] = wt_fh_vh;   wa.dstl[6] = wt_fh_vl;   wa.nout[6] = 512;
    wa.src[7] = W_fh_l;   wa.dsth[7] = wt_fh_lh;   wa.dstl[7] = wt_fh_ll;   wa.nout[7] = 512;
    prep<<<1543, 256, 0, stream>>>(wa, sel, perm_g, inv_g, lvlPerm, lvlInv, cnt);

    // ---- one mega kernel for everything else ----
    Mega m{};
    m.pre0 = GSet{xh, xl, wt_ioux_lh, wt_ioux_ll, wt_ioux_vh, wt_ioux_vl,
                  b_ioux_l, b_ioux_v, iou_pre, perm_g, 0, N_NODES, 1536};
    m.pre1 = GSet{xh, xl, wt_fx_lh, wt_fx_ll, wt_fx_vh, wt_fx_vl,
                  b_fx_l, b_fx_v, fx_pre, perm_g, 0, N_NODES, 512};
    m.lv0  = GSet{hs_h, hs_l, wt_iouh_lh, wt_iouh_ll, wt_iouh_vh, wt_iouh_vl,
                  b_iouh_l, b_iouh_v, iou_h, nullptr, 0, 0, 1536};
    m.lv1  = GSet{ch_h, ch_l, wt_fh_lh, wt_fh_ll, wt_fh_vh, wt_fh_vl,
                  b_fh_l, b_fh_v, fpre, nullptr, 0, 0, 512};
    m.cnt = cnt;
    m.iou_pre = iou_pre; m.fx_pre = fx_pre;
    m.iou_h = iou_h; m.fpre = fpre; m.c_all = c_all; m.h_all = h_all;
    m.children = children; m.lvlPerm = lvlPerm; m.lvlInv = lvlInv; m.inv_g = inv_g;
    m.b_iouh_v = b_iouh_v; m.b_iouh_l = b_iouh_l;
    m.hs_h = hs_h; m.hs_l = hs_l; m.ch_h = ch_h; m.ch_l = ch_l;
    m.sync = gsync;
    mega<<<512, 512, 0, stream>>>(m);
}

// Round 10
// 698.506 us; speedup vs baseline: 2.8004x; 2.8004x over previous
//
#include <hip/hip_runtime.h>
#include <cstdint>

constexpr int N_NODES = 5461;

using f16x8 = __attribute__((ext_vector_type(8))) _Float16;
using f32x4 = __attribute__((ext_vector_type(4))) float;

typedef const __attribute__((address_space(1))) unsigned int* gas_p;
typedef __attribute__((address_space(3))) unsigned int* las_p;

__device__ __forceinline__ float sigm(float v) { return 1.0f / (1.0f + __expf(-v)); }

__constant__ int d_STARTS[8] = {0, 1, 5, 21, 85, 341, 1365, 5461};

// ---------------- split-fp16 MFMA GEMM tile (device body; verified r8) ----------------
// 512 threads = 8 waves (2M x 4N), wave tile 64x32, block tile 128x128, K=512, 16 steps.
// LDS chunk-XOR swizzle: row r's 16B chunk c at slot c^((r>>1)&3); staged via
// inverse-permuted GLOBAL source (LDS dest linear); read slot kg^((rsel>>1)&3). 0 conflicts.
struct GSet {
    const _Float16 *Ah, *Al;
    const _Float16 *BhL, *BlL, *BhV, *BlV;
    const float *biasL, *biasV;
    float* Y;
    const int* permA;      // null => identity
    int nL, M, Nout;       // nL filled at runtime from cnt
};

__device__ void gemm_tile(const GSet& S, int tx, int bn)
{
    const int nTl = (S.nL + 127) >> 7;
    int rowBase, rowEnd;
    const _Float16 *Bh, *Bl;
    const float* bias;
    if (tx < nTl) {
        rowBase = tx << 7; rowEnd = S.nL;
        Bh = S.BhL; Bl = S.BlL; bias = S.biasL;
    } else {
        rowBase = S.nL + ((tx - nTl) << 7); rowEnd = S.M;
        Bh = S.BhV; Bl = S.BlV; bias = S.biasV;
    }
    if (rowBase >= rowEnd) return;

    __shared__ _Float16 AsH[2][128 * 32];
    __shared__ _Float16 AsL[2][128 * 32];
    __shared__ _Float16 BsH[2][128 * 32];
    __shared__ _Float16 BsL[2][128 * 32];

    const int tid = threadIdx.x;
    const int wid = tid >> 6;          // 0..7
    const int lane = tid & 63;
    const int wm = (wid >> 2) * 64;
    const int wn = (wid & 3) * 32;
    const int rsel = lane & 15;
    const int kg = lane >> 4;
    const int lrow = lane >> 2;
    const int csrc = ((lane & 3) ^ ((lane >> 3) & 3)) * 8;
    int aR = rowBase + wid * 16 + lrow; if (aR > rowEnd - 1) aR = rowEnd - 1;
    const int a0 = S.permA ? S.permA[aR] : aR;
    const _Float16* gAh = S.Ah + (size_t)a0 * 512 + csrc;
    const _Float16* gAl = S.Al + (size_t)a0 * 512 + csrc;
    const _Float16* gBh = Bh + (size_t)(bn + wid * 16 + lrow) * 512 + csrc;
    const _Float16* gBl = Bl + (size_t)(bn + wid * 16 + lrow) * 512 + csrc;

    f32x4 acc0[4][2] = {};
    f32x4 acc1[4][2] = {};

    auto stage = [&](int k0, int b) {
        __builtin_amdgcn_global_load_lds((gas_p)(const void*)(gAh + k0), (las_p)(void*)(&AsH[b][wid * 512]), 16, 0, 0);
        __builtin_amdgcn_global_load_lds((gas_p)(const void*)(gAl + k0), (las_p)(void*)(&AsL[b][wid * 512]), 16, 0, 0);
        __builtin_amdgcn_global_load_lds((gas_p)(const void*)(gBh + k0), (las_p)(void*)(&BsH[b][wid * 512]), 16, 0, 0);
        __builtin_amdgcn_global_load_lds((gas_p)(const void*)(gBl + k0), (las_p)(void*)(&BsL[b][wid * 512]), 16, 0, 0);
    };

    const int sl = kg ^ ((rsel >> 1) & 3);

    stage(0, 0);
    __syncthreads();
#pragma unroll 1
    for (int step = 0; step < 16; ++step) {
        const int cur = step & 1;
        if (step < 15) stage((step + 1) * 32, cur ^ 1);
        const f16x8* AH = (const f16x8*)AsH[cur];
        const f16x8* AL = (const f16x8*)AsL[cur];
        const f16x8* BH = (const f16x8*)BsH[cur];
        const f16x8* BL = (const f16x8*)BsL[cur];
        f16x8 bh[2], bl[2];
#pragma unroll
        for (int j = 0; j < 2; ++j) {
            int bi = (wn + j * 16 + rsel) * 4 + sl;
            bh[j] = BH[bi];
            bl[j] = BL[bi];
        }
#pragma unroll
        for (int i = 0; i < 4; ++i) {
            int ai = (wm + i * 16 + rsel) * 4 + sl;
            f16x8 ah = AH[ai];
            f16x8 al = AL[ai];
#pragma unroll
            for (int j = 0; j < 2; ++j) {
                acc0[i][j] = __builtin_amdgcn_mfma_f32_16x16x32_f16(ah, bh[j], acc0[i][j], 0, 0, 0);
                acc1[i][j] = __builtin_amdgcn_mfma_f32_16x16x32_f16(ah, bl[j], acc1[i][j], 0, 0, 0);
                acc1[i][j] = __builtin_amdgcn_mfma_f32_16x16x32_f16(al, bh[j], acc1[i][j], 0, 0, 0);
            }
        }
        __syncthreads();
    }

    // C/D layout: col=lane&15, row=(lane>>4)*4+reg  [HW-verified]
#pragma unroll
    for (int i = 0; i < 4; ++i) {
        int row0 = rowBase + wm + i * 16 + kg * 4;
#pragma unroll
        for (int j = 0; j < 2; ++j) {
            int col = bn + wn + j * 16 + rsel;
            float bb = bias[col];
#pragma unroll
            for (int r = 0; r < 4; ++r) {
                int row = row0 + r;
                if (row < rowEnd)
                    S.Y[(size_t)row * S.Nout + col] = acc0[i][j][r] + acc1[i][j][r] * (1.0f / 2048.0f) + bb;
            }
        }
    }
}

// ---------------- device-wide barrier (fixed r10) ----------------
// RELEASE on the add (one wbl2 per block/phase), RELAXED spin (no invalidate!),
// single ACQUIRE load after exit (one buffer_inv per block/phase). The r9 version
// acquired on EVERY spin iteration -> chip-wide L2-invalidate storm (8x regression).
__device__ __forceinline__ void gbar(int* c, int nb)
{
    __syncthreads();
    if (threadIdx.x == 0) {
        __hip_atomic_fetch_add(c, 1, __ATOMIC_RELEASE, __HIP_MEMORY_SCOPE_AGENT);
        while (__hip_atomic_load(c, __ATOMIC_RELAXED, __HIP_MEMORY_SCOPE_AGENT) < nb)
            __builtin_amdgcn_s_sleep(32);
        int v = __hip_atomic_load(c, __ATOMIC_ACQUIRE, __HIP_MEMORY_SCOPE_AGENT);
        asm volatile("" :: "s"(v));    // keep the acquire load live
    }
    __syncthreads();
}

// ---------------- mega kernel: precompute GEMM + full tree tail, one launch ----------------
struct Mega {
    GSet pre0, pre1;     // x @ W_ioux / W_fx (permA = perm_g)
    GSet lv0, lv1;       // hs @ W_iouh / ch @ W_fh (per-level M filled in kernel)
    const int* cnt;      // cnt[0]=global langs, cnt[1+l]=level-l langs
    const float *iou_pre, *fx_pre;
    float *iou_h, *fpre, *c_all, *h_all;
    const int *children, *lvlPerm, *lvlInv, *inv_g;
    const float *b_iouh_v, *b_iouh_l;
    _Float16 *hs_h, *hs_l, *ch_h, *ch_l;
    int* sync;
};

__device__ void leaf_body(const Mega& m, int w, int t)
{
    const int ip = w;                           // 0..1023 level-5 parent slots
    const int p = m.lvlPerm[341 + ip];
    const int d0 = t * 2;
    const int nLg = m.cnt[0];
    float hsum[2] = {0.f, 0.f};
#pragma unroll
    for (int k = 0; k < 4; ++k) {
        int cnode = m.children[p * 4 + k];
        int u = m.inv_g[cnode];
        const float* bh = (u < nLg) ? m.b_iouh_l : m.b_iouh_v;
        size_t ub = (size_t)u * 1536;
#pragma unroll
        for (int e = 0; e < 2; ++e) {
            int d = d0 + e;
            float iv = m.iou_pre[ub + d]        + bh[d];
            float ov = m.iou_pre[ub + 512 + d]  + bh[512 + d];
            float uv = m.iou_pre[ub + 1024 + d] + bh[1024 + d];
            float cc = sigm(iv) * tanhf(uv);
            float hh = sigm(ov) * tanhf(cc);
            m.c_all[(size_t)cnode * 512 + d] = cc;
            m.h_all[(size_t)cnode * 512 + d] = hh;
            hsum[e] += hh;
            _Float16 hf = (_Float16)hh;
            size_t o = ((size_t)(ip * 4 + k)) * 512 + d;
            m.ch_h[o] = hf;
            m.ch_l[o] = (_Float16)((hh - (float)hf) * 2048.0f);
        }
    }
#pragma unroll
    for (int e = 0; e < 2; ++e) {
        _Float16 sh = (_Float16)hsum[e];
        m.hs_h[(size_t)ip * 512 + d0 + e] = sh;
        m.hs_l[(size_t)ip * 512 + d0 + e] = (_Float16)((hsum[e] - (float)sh) * 2048.0f);
    }
}

__device__ void combine_body(const Mega& m, int l, int w, int t)
{
    const int sPar = d_STARTS[l - 1];
    const int sLvl = d_STARTS[l];
    const int nPar = sLvl - sPar;
    const int d0 = t * 2;
    for (int ip = w; ip < nPar; ip += 1024) {
        int p = m.lvlPerm[sPar + ip];
        float hsum[2] = {0.f, 0.f};
#pragma unroll
        for (int k = 0; k < 4; ++k) {
            int cnode = m.children[p * 4 + k];
            int j = m.lvlInv[cnode] - sLvl;
            int u = m.inv_g[cnode];
            size_t ub = (size_t)u * 1536;
            size_t jb = (size_t)j * 1536;
#pragma unroll
            for (int e = 0; e < 2; ++e) {
                int d = d0 + e;
                float iv = m.iou_pre[ub + d]        + m.iou_h[jb + d];
                float ov = m.iou_pre[ub + 512 + d]  + m.iou_h[jb + 512 + d];
                float uv = m.iou_pre[ub + 1024 + d] + m.iou_h[jb + 1024 + d];
                float fxn = m.fx_pre[(size_t)u * 512 + d];
                float csum = 0.f;
#pragma unroll
                for (int k2 = 0; k2 < 4; ++k2) {
                    int gc = m.children[cnode * 4 + k2];
                    float f = sigm(m.fpre[((size_t)(j * 4 + k2)) * 512 + d] + fxn);
                    csum = fmaf(f, m.c_all[(size_t)gc * 512 + d], csum);
                }
                float cc = sigm(iv) * tanhf(uv) + csum;
                float hh = sigm(ov) * tanhf(cc);
                m.c_all[(size_t)cnode * 512 + d] = cc;
                m.h_all[(size_t)cnode * 512 + d] = hh;
                hsum[e] += hh;
                _Float16 hf = (_Float16)hh;
                size_t o = ((size_t)(ip * 4 + k)) * 512 + d;
                m.ch_h[o] = hf;
                m.ch_l[o] = (_Float16)((hh - (float)hf) * 2048.0f);
            }
        }
#pragma unroll
        for (int e = 0; e < 2; ++e) {
            _Float16 sh = (_Float16)hsum[e];
            m.hs_h[(size_t)ip * 512 + d0 + e] = sh;
            m.hs_l[(size_t)ip * 512 + d0 + e] = (_Float16)((hsum[e] - (float)sh) * 2048.0f);
        }
    }
}

__device__ void root_body(const Mega& m, int w, int t)
{
    if (w >= 2) return;
    int d = w * 256 + t;
    int u = m.inv_g[0];
    size_t ub = (size_t)u * 1536;
    float iv = m.iou_pre[ub + d]        + m.iou_h[d];
    float ov = m.iou_pre[ub + 512 + d]  + m.iou_h[512 + d];
    float uv = m.iou_pre[ub + 1024 + d] + m.iou_h[1024 + d];
    float fxn = m.fx_pre[(size_t)u * 512 + d];
    float csum = 0.f;
#pragma unroll
    for (int k = 0; k < 4; ++k) {
        int gc = m.children[k];
        float f = sigm(m.fpre[(size_t)k * 512 + d] + fxn);
        csum = fmaf(f, m.c_all[(size_t)gc * 512 + d], csum);
    }
    float cc = sigm(iv) * tanhf(uv) + csum;
    float hh = sigm(ov) * tanhf(cc);
    m.c_all[d] = cc;
    m.h_all[d] = hh;
}

__device__ void level_gemm(const Mega& m, int l, int nb)
{
    const int E = d_STARTS[l + 1] - d_STARTS[l];
    const int langs = m.cnt[1 + l];
    GSet s0 = m.lv0; s0.nL = langs;     s0.M = E;
    GSet s1 = m.lv1; s1.nL = langs * 4; s1.M = E * 4;
    const int gx = (E * 4 + 127) / 128 + 1;
    for (int f = blockIdx.x; f < gx * 16; f += nb) {
        int ty = f & 15, tx = f >> 4;
        if (ty < 12) gemm_tile(s0, tx, ty * 128);
        else         gemm_tile(s1, tx, (ty - 12) * 128);
    }
}

__global__ __launch_bounds__(512, 4)
void mega(Mega m)
{
    const int nb = gridDim.x;
    const int w = blockIdx.x * 2 + (threadIdx.x >> 8);
    const int t = threadIdx.x & 255;

    // ---- phase 0: precompute GEMMs (ioux 12 col-tiles + fx 4 col-tiles) ----
    {
        GSet s0 = m.pre0; s0.nL = m.cnt[0];
        GSet s1 = m.pre1; s1.nL = m.cnt[0];
        const int gx = (N_NODES + 127) / 128 + 1;   // 44
        for (int f = blockIdx.x; f < gx * 16; f += nb) {
            int ty = f & 15, tx = f >> 4;
            if (ty < 12) gemm_tile(s0, tx, ty * 128);
            else         gemm_tile(s1, tx, (ty - 12) * 128);
        }
    }
    gbar(m.sync + 0, nb);

    // ---- phase 1: leaves + gather(level 5) ----
    leaf_body(m, w, t);
    gbar(m.sync + 1, nb);

    int ph = 2;
#pragma unroll 1
    for (int l = 5; l >= 1; --l) {
        level_gemm(m, l, nb);
        gbar(m.sync + ph, nb); ++ph;
        combine_body(m, l, w, t);
        gbar(m.sync + ph, nb); ++ph;
    }
    level_gemm(m, 0, nb);
    gbar(m.sync + 12, nb);
    root_body(m, w, t);
}

// ---------------- fused: x -> fp16 hi/lo split + type-selector logits ----------------
__global__ __launch_bounds__(256)
void cast_x_sel(const float* __restrict__ x, const float* __restrict__ Wt,
                const float* __restrict__ bt,
                _Float16* __restrict__ hi, _Float16* __restrict__ lo,
                int* __restrict__ sel)
{
    __shared__ float s0[256], s1[256];
    int t = threadIdx.x;
    int row = blockIdx.x * 2 + (t >> 7);
    int c0 = (t & 127) * 4;
    float p0 = 0.f, p1 = 0.f;
    if (row < N_NODES) {
        size_t off = (size_t)row * 512 + c0;
        float4 v = *(const float4*)(x + off);
        float vv[4] = {v.x, v.y, v.z, v.w};
        union { _Float16 h[4]; ushort4 u; } H, L;
#pragma unroll
        for (int i = 0; i < 4; ++i) {
            _Float16 h = (_Float16)vv[i];
            H.h[i] = h;
            L.h[i] = (_Float16)((vv[i] - (float)h) * 2048.0f);
            p0 = fmaf(vv[i], Wt[(c0 + i) * 2], p0);
            p1 = fmaf(vv[i], Wt[(c0 + i) * 2 + 1], p1);
        }
        *(ushort4*)(hi + off) = H.u;
        *(ushort4*)(lo + off) = L.u;
    }
    s0[t] = p0; s1[t] = p1;
    __syncthreads();
    for (int st = 64; st > 0; st >>= 1) {
        if ((t & 127) < st) { s0[t] += s0[t + st]; s1[t] += s1[t + st]; }
        __syncthreads();
    }
    if ((t & 127) == 0 && row < N_NODES)
        sel[row] = (s0[t] + bt[0] >= s1[t] + bt[1]) ? 1 : 0;
}

// ---------------- prep: transpose+split-cast weights (blocks 0..1535) | partition (1536..1542) ----------------
struct WtArgs {
    const float* src[8];
    _Float16* dsth[8];
    _Float16* dstl[8];
    int nout[8];
};

__global__ __launch_bounds__(256)
void prep(WtArgs a, const int* __restrict__ sel, int* __restrict__ perm_g,
          int* __restrict__ inv_g, int* __restrict__ lvlPerm,
          int* __restrict__ lvlInv, int* __restrict__ cnt)
{
    if (blockIdx.x < 1536) {
        int idx = blockIdx.x;
        int mi = idx / 192;
        int r = idx % 192;
        int n0 = (r >> 3) * 64;
        int k0 = (r & 7) * 64;
        int Nout = a.nout[mi];
        if (n0 >= Nout) return;
        const float* W = a.src[mi];
        _Float16* TH = a.dsth[mi];
        _Float16* TL = a.dstl[mi];
        __shared__ float tbuf[64][65];
        int tx = threadIdx.x & 63, ty = threadIdx.x >> 6;
#pragma unroll
        for (int rr = ty; rr < 64; rr += 4)
            tbuf[rr][tx] = W[(size_t)(k0 + rr) * Nout + n0 + tx];
        __syncthreads();
#pragma unroll
        for (int rr = ty; rr < 64; rr += 4) {
            float v = tbuf[tx][rr];
            _Float16 h = (_Float16)v;
            TH[(size_t)(n0 + rr) * 512 + k0 + tx] = h;
            TL[(size_t)(n0 + rr) * 512 + k0 + tx] = (_Float16)((v - (float)h) * 2048.0f);
        }
    } else {
        __shared__ int ps[256];
        int b = blockIdx.x - 1536;        // 0..6
        int s, e;
        if (b == 0) { s = 0; e = N_NODES; }
        else { s = d_STARTS[b - 1]; e = d_STARTS[b]; }
        int E = e - s;
        int t = threadIdx.x;
        int chunk = (E + 255) / 256;
        int beg = min(t * chunk, E);
        int end = min(beg + chunk, E);
        int c = 0;
        for (int i = beg; i < end; ++i) c += sel[s + i];
        ps[t] = c;
        __syncthreads();
        for (int off = 1; off < 256; off <<= 1) {
            int other = (t >= off) ? ps[t - off] : 0;
            __syncthreads();
            ps[t] += other;
            __syncthreads();
        }
        int total = ps[255];
        int excl = ps[t] - c;
        int pL = excl;
        int pV = total + (beg - excl);
        for (int i = beg; i < end; ++i) {
            int node = s + i;
            int pos = sel[node] ? pL++ : pV++;
            int slot = s + pos;
            if (b == 0) { perm_g[slot] = node; inv_g[node] = slot; }
            else { lvlPerm[slot] = node; lvlInv[node] = slot; }
        }
        if (t == 0) cnt[b] = total;
    }
}

extern "C" void kernel_launch(void* const* d_in, const int* in_sizes, int n_in,
                              void* d_out, int out_size, void* d_ws, size_t ws_size,
                              hipStream_t stream)
{
    const float* x        = (const float*)d_in[0];
    const int*   children = (const int*)  d_in[1];
    const float* W_ioux_v = (const float*)d_in[2];
    const float* b_ioux_v = (const float*)d_in[3];
    const float* W_iouh_v = (const float*)d_in[4];
    const float* b_iouh_v = (const float*)d_in[5];
    const float* W_fx_v   = (const float*)d_in[6];
    const float* b_fx_v   = (const float*)d_in[7];
    const float* W_fh_v   = (const float*)d_in[8];
    const float* b_fh_v   = (const float*)d_in[9];
    const float* W_ioux_l = (const float*)d_in[10];
    const float* b_ioux_l = (const float*)d_in[11];
    const float* W_iouh_l = (const float*)d_in[12];
    const float* b_iouh_l = (const float*)d_in[13];
    const float* W_fx_l   = (const float*)d_in[14];
    const float* b_fx_l   = (const float*)d_in[15];
    const float* W_fh_l   = (const float*)d_in[16];
    const float* b_fh_l   = (const float*)d_in[17];
    const float* W_type   = (const float*)d_in[18];
    const float* b_type   = (const float*)d_in[19];
    float* h_all = (float*)d_out;

    // ---- workspace carve-up ----
    float* p = (float*)d_ws;
    float* iou_pre = p; p += (size_t)N_NODES * 1536;
    float* fx_pre  = p; p += (size_t)N_NODES * 512;
    float* c_all   = p; p += (size_t)N_NODES * 512;
    float* iou_h   = p; p += (size_t)1024 * 1536;
    float* fpre    = p; p += (size_t)4096 * 512;
    int* sel     = (int*)p; p += 6144;
    int* perm_g  = (int*)p; p += 6144;
    int* inv_g   = (int*)p; p += 6144;
    int* lvlPerm = (int*)p; p += 2048;
    int* lvlInv  = (int*)p; p += 2048;
    int* cnt     = (int*)p; p += 64;
    int* gsync   = (int*)p; p += 64;
    _Float16* q = (_Float16*)p;
    _Float16* xh   = q; q += (size_t)N_NODES * 512;
    _Float16* xl   = q; q += (size_t)N_NODES * 512;
    _Float16* hs_h = q; q += (size_t)1024 * 512;
    _Float16* hs_l = q; q += (size_t)1024 * 512;
    _Float16* ch_h = q; q += (size_t)4096 * 512;
    _Float16* ch_l = q; q += (size_t)4096 * 512;
    _Float16* wt_ioux_vh = q; q += (size_t)1536 * 512;
    _Float16* wt_ioux_vl = q; q += (size_t)1536 * 512;
    _Float16* wt_ioux_lh = q; q += (size_t)1536 * 512;
    _Float16* wt_ioux_ll = q; q += (size_t)1536 * 512;
    _Float16* wt_iouh_vh = q; q += (size_t)1536 * 512;
    _Float16* wt_iouh_vl = q; q += (size_t)1536 * 512;
    _Float16* wt_iouh_lh = q; q += (size_t)1536 * 512;
    _Float16* wt_iouh_ll = q; q += (size_t)1536 * 512;
    _Float16* wt_fx_vh   = q; q += (size_t)512 * 512;
    _Float16* wt_fx_vl   = q; q += (size_t)512 * 512;
    _Float16* wt_fx_lh   = q; q += (size_t)512 * 512;
    _Float16* wt_fx_ll   = q; q += (size_t)512 * 512;
    _Float16* wt_fh_vh   = q; q += (size_t)512 * 512;
    _Float16* wt_fh_vl   = q; q += (size_t)512 * 512;
    _Float16* wt_fh_lh   = q; q += (size_t)512 * 512;
    _Float16* wt_fh_ll   = q; q += (size_t)512 * 512;

    // ---- reset barrier counters (captured; runs every replay) ----
    hipMemsetAsync(gsync, 0, 64 * sizeof(int), stream);

    cast_x_sel<<<(N_NODES + 1) / 2, 256, 0, stream>>>(x, W_type, b_type, xh, xl, sel);

    WtArgs wa;
    wa.src[0] = W_ioux_v; wa.dsth[0] = wt_ioux_vh; wa.dstl[0] = wt_ioux_vl; wa.nout[0] = 1536;
    wa.src[1] = W_ioux_l; wa.dsth[1] = wt_ioux_lh; wa.dstl[1] = wt_ioux_ll; wa.nout[1] = 1536;
    wa.src[2] = W_iouh_v; wa.dsth[2] = wt_iouh_vh; wa.dstl[2] = wt_iouh_vl; wa.nout[2] = 1536;
    wa.src[3] = W_iouh_l; wa.dsth[3] = wt_iouh_lh; wa.dstl[3] = wt_iouh_ll; wa.nout[3] = 1536;
    wa.src[4] = W_fx_v;   wa.dsth[4] = wt_fx_vh;   wa.dstl[4] = wt_fx_vl;   wa.nout[4] = 512;
    wa.src[5] = W_fx_l;   wa.dsth[5] = wt_fx_lh;   wa.dstl[5] = wt_fx_ll;   wa.nout[5] = 512;
    wa.src[6] = W_fh_v;   wa.dsth[6] = wt_fh_vh;   wa.dstl[6] = wt_fh_vl;   wa.nout[6] = 512;
    wa.src[7] = W_fh_l;   wa.dsth[7] = wt_fh_lh;   wa.dstl[7] = wt_fh_ll;   wa.nout[7] = 512;
    prep<<<1543, 256, 0, stream>>>(wa, sel, perm_g, inv_g, lvlPerm, lvlInv, cnt);

    // ---- one mega kernel for everything else ----
    Mega m{};
    m.pre0 = GSet{xh, xl, wt_ioux_lh, wt_ioux_ll, wt_ioux_vh, wt_ioux_vl,
                  b_ioux_l, b_ioux_v, iou_pre, perm_g, 0, N_NODES, 1536};
    m.pre1 = GSet{xh, xl, wt_fx_lh, wt_fx_ll, wt_fx_vh, wt_fx_vl,
                  b_fx_l, b_fx_v, fx_pre, perm_g, 0, N_NODES, 512};
    m.lv0  = GSet{hs_h, hs_l, wt_iouh_lh, wt_iouh_ll, wt_iouh_vh, wt_iouh_vl,
                  b_iouh_l, b_iouh_v, iou_h, nullptr, 0, 0, 1536};
    m.lv1  = GSet{ch_h, ch_l, wt_fh_lh, wt_fh_ll, wt_fh_vh, wt_fh_vl,
                  b_fh_l, b_fh_v, fpre, nullptr, 0, 0, 512};
    m.cnt = cnt;
    m.iou_pre = iou_pre; m.fx_pre = fx_pre;
    m.iou_h = iou_h; m.fpre = fpre; m.c_all = c_all; m.h_all = h_all;
    m.children = children; m.lvlPerm = lvlPerm; m.lvlInv = lvlInv; m.inv_g = inv_g;
    m.b_iouh_v = b_iouh_v; m.b_iouh_l = b_iouh_l;
    m.hs_h = hs_h; m.hs_l = hs_l; m.ch_h = ch_h; m.ch_l = ch_l;
    m.sync = gsync;
    mega<<<512, 512, 0, stream>>>(m);
}

// Round 11
// 280.858 us; speedup vs baseline: 6.9647x; 2.4870x over previous
//
#include <hip/hip_runtime.h>
#include <cstdint>

constexpr int N_NODES = 5461;

using f16x8 = __attribute__((ext_vector_type(8))) _Float16;
using f32x4 = __attribute__((ext_vector_type(4))) float;

typedef const __attribute__((address_space(1))) unsigned int* gas_p;
typedef __attribute__((address_space(3))) unsigned int* las_p;

__device__ __forceinline__ float sigm(float v) { return 1.0f / (1.0f + __expf(-v)); }

__constant__ int d_STARTS[8] = {0, 1, 5, 21, 85, 341, 1365, 5461};

// ================= split-fp16 MFMA GEMM tile (device body; verified r8) =================
// 512 threads = 8 waves (2M x 4N), wave tile 64x32, block tile 128x128, K=512, 16 steps.
// LDS chunk-XOR swizzle: row r's 16B chunk c at slot c^((r>>1)&3); staged via
// inverse-permuted GLOBAL source (LDS dest linear); read slot kg^((rsel>>1)&3). 0 conflicts.
struct GSet {
    const _Float16 *Ah, *Al;
    const _Float16 *BhL, *BlL, *BhV, *BlV;
    const float *biasL, *biasV;
    float* Y;
    const int* permA;      // null => identity
    int nL, M, Nout;
};

__device__ void gemm_tile(const GSet& S, int tx, int bn)
{
    const int nTl = (S.nL + 127) >> 7;
    int rowBase, rowEnd;
    const _Float16 *Bh, *Bl;
    const float* bias;
    if (tx < nTl) {
        rowBase = tx << 7; rowEnd = S.nL;
        Bh = S.BhL; Bl = S.BlL; bias = S.biasL;
    } else {
        rowBase = S.nL + ((tx - nTl) << 7); rowEnd = S.M;
        Bh = S.BhV; Bl = S.BlV; bias = S.biasV;
    }
    if (rowBase >= rowEnd) return;

    __shared__ _Float16 AsH[2][128 * 32];
    __shared__ _Float16 AsL[2][128 * 32];
    __shared__ _Float16 BsH[2][128 * 32];
    __shared__ _Float16 BsL[2][128 * 32];

    const int tid = threadIdx.x;
    const int wid = tid >> 6;
    const int lane = tid & 63;
    const int wm = (wid >> 2) * 64;
    const int wn = (wid & 3) * 32;
    const int rsel = lane & 15;
    const int kg = lane >> 4;
    const int lrow = lane >> 2;
    const int csrc = ((lane & 3) ^ ((lane >> 3) & 3)) * 8;
    int aR = rowBase + wid * 16 + lrow; if (aR > rowEnd - 1) aR = rowEnd - 1;
    const int a0 = S.permA ? S.permA[aR] : aR;
    const _Float16* gAh = S.Ah + (size_t)a0 * 512 + csrc;
    const _Float16* gAl = S.Al + (size_t)a0 * 512 + csrc;
    const _Float16* gBh = Bh + (size_t)(bn + wid * 16 + lrow) * 512 + csrc;
    const _Float16* gBl = Bl + (size_t)(bn + wid * 16 + lrow) * 512 + csrc;

    f32x4 acc0[4][2] = {};
    f32x4 acc1[4][2] = {};

    auto stage = [&](int k0, int b) {
        __builtin_amdgcn_global_load_lds((gas_p)(const void*)(gAh + k0), (las_p)(void*)(&AsH[b][wid * 512]), 16, 0, 0);
        __builtin_amdgcn_global_load_lds((gas_p)(const void*)(gAl + k0), (las_p)(void*)(&AsL[b][wid * 512]), 16, 0, 0);
        __builtin_amdgcn_global_load_lds((gas_p)(const void*)(gBh + k0), (las_p)(void*)(&BsH[b][wid * 512]), 16, 0, 0);
        __builtin_amdgcn_global_load_lds((gas_p)(const void*)(gBl + k0), (las_p)(void*)(&BsL[b][wid * 512]), 16, 0, 0);
    };

    const int sl = kg ^ ((rsel >> 1) & 3);

    stage(0, 0);
    __syncthreads();
#pragma unroll 1
    for (int step = 0; step < 16; ++step) {
        const int cur = step & 1;
        if (step < 15) stage((step + 1) * 32, cur ^ 1);
        const f16x8* AH = (const f16x8*)AsH[cur];
        const f16x8* AL = (const f16x8*)AsL[cur];
        const f16x8* BH = (const f16x8*)BsH[cur];
        const f16x8* BL = (const f16x8*)BsL[cur];
        f16x8 bh[2], bl[2];
#pragma unroll
        for (int j = 0; j < 2; ++j) {
            int bi = (wn + j * 16 + rsel) * 4 + sl;
            bh[j] = BH[bi];
            bl[j] = BL[bi];
        }
#pragma unroll
        for (int i = 0; i < 4; ++i) {
            int ai = (wm + i * 16 + rsel) * 4 + sl;
            f16x8 ah = AH[ai];
            f16x8 al = AL[ai];
#pragma unroll
            for (int j = 0; j < 2; ++j) {
                acc0[i][j] = __builtin_amdgcn_mfma_f32_16x16x32_f16(ah, bh[j], acc0[i][j], 0, 0, 0);
                acc1[i][j] = __builtin_amdgcn_mfma_f32_16x16x32_f16(ah, bl[j], acc1[i][j], 0, 0, 0);
                acc1[i][j] = __builtin_amdgcn_mfma_f32_16x16x32_f16(al, bh[j], acc1[i][j], 0, 0, 0);
            }
        }
        __syncthreads();
    }

    // C/D layout: col=lane&15, row=(lane>>4)*4+reg  [HW-verified]
#pragma unroll
    for (int i = 0; i < 4; ++i) {
        int row0 = rowBase + wm + i * 16 + kg * 4;
#pragma unroll
        for (int j = 0; j < 2; ++j) {
            int col = bn + wn + j * 16 + rsel;
            float bb = bias[col];
#pragma unroll
            for (int r = 0; r < 4; ++r) {
                int row = row0 + r;
                if (row < rowEnd)
                    S.Y[(size_t)row * S.Nout + col] = acc0[i][j][r] + acc1[i][j][r] * (1.0f / 2048.0f) + bb;
            }
        }
    }
}

// ================= standalone paired GEMM launch (r8 verified) =================
struct GP {
    GSet s0, s1;
    const int* cntPtr;
    int cntScale0, cntScale1;
    int yT0;
};

__global__ __launch_bounds__(512, 4)
void gemm_pair(GP g)
{
    GSet S;
    int bn;
    if (blockIdx.y < (unsigned)g.yT0) {
        S = g.s0; S.nL = g.cntPtr[0] * g.cntScale0;
        bn = blockIdx.y * 128;
    } else {
        S = g.s1; S.nL = g.cntPtr[0] * g.cntScale1;
        bn = (blockIdx.y - g.yT0) * 128;
    }
    gemm_tile(S, blockIdx.x, bn);
}

// ================= device-wide barrier (r10-fixed: 1 release + relaxed spin + 1 acquire) ===========
__device__ __forceinline__ void gbar(int* c, int nb)
{
    __syncthreads();
    if (threadIdx.x == 0) {
        __hip_atomic_fetch_add(c, 1, __ATOMIC_RELEASE, __HIP_MEMORY_SCOPE_AGENT);
        while (__hip_atomic_load(c, __ATOMIC_RELAXED, __HIP_MEMORY_SCOPE_AGENT) < nb)
            __builtin_amdgcn_s_sleep(16);
        int v = __hip_atomic_load(c, __ATOMIC_ACQUIRE, __HIP_MEMORY_SCOPE_AGENT);
        asm volatile("" :: "s"(v));
    }
    __syncthreads();
}

// ================= shared context for fused bodies =================
struct Ctx {
    GSet lv0, lv1;        // hs @ W_iouh / ch @ W_fh (nL/M filled per level)
    const int* cnt;
    const float *iou_pre, *fx_pre;
    float *iou_h, *fpre, *c_all, *h_all;
    const int *children, *lvlPerm, *lvlInv, *inv_g;
    const float *b_iouh_v, *b_iouh_l;
    _Float16 *hs_h, *hs_l, *ch_h, *ch_l;
    int* sync;
};

__device__ void combine_body(const Ctx& m, int l, int w, int t, int nw)
{
    const int sPar = d_STARTS[l - 1];
    const int sLvl = d_STARTS[l];
    const int nPar = sLvl - sPar;
    const int d0 = t * 2;
    for (int ip = w; ip < nPar; ip += nw) {
        int p = m.lvlPerm[sPar + ip];
        float hsum[2] = {0.f, 0.f};
#pragma unroll
        for (int k = 0; k < 4; ++k) {
            int cnode = m.children[p * 4 + k];
            int j = m.lvlInv[cnode] - sLvl;
            int u = m.inv_g[cnode];
            size_t ub = (size_t)u * 1536;
            size_t jb = (size_t)j * 1536;
#pragma unroll
            for (int e = 0; e < 2; ++e) {
                int d = d0 + e;
                float iv = m.iou_pre[ub + d]        + m.iou_h[jb + d];
                float ov = m.iou_pre[ub + 512 + d]  + m.iou_h[jb + 512 + d];
                float uv = m.iou_pre[ub + 1024 + d] + m.iou_h[jb + 1024 + d];
                float fxn = m.fx_pre[(size_t)u * 512 + d];
                float csum = 0.f;
#pragma unroll
                for (int k2 = 0; k2 < 4; ++k2) {
                    int gc = m.children[cnode * 4 + k2];
                    float f = sigm(m.fpre[((size_t)(j * 4 + k2)) * 512 + d] + fxn);
                    csum = fmaf(f, m.c_all[(size_t)gc * 512 + d], csum);
                }
                float cc = sigm(iv) * tanhf(uv) + csum;
                float hh = sigm(ov) * tanhf(cc);
                m.c_all[(size_t)cnode * 512 + d] = cc;
                m.h_all[(size_t)cnode * 512 + d] = hh;
                hsum[e] += hh;
                _Float16 hf = (_Float16)hh;
                size_t o = ((size_t)(ip * 4 + k)) * 512 + d;
                m.ch_h[o] = hf;
                m.ch_l[o] = (_Float16)((hh - (float)hf) * 2048.0f);
            }
        }
#pragma unroll
        for (int e = 0; e < 2; ++e) {
            _Float16 sh = (_Float16)hsum[e];
            m.hs_h[(size_t)ip * 512 + d0 + e] = sh;
            m.hs_l[(size_t)ip * 512 + d0 + e] = (_Float16)((hsum[e] - (float)sh) * 2048.0f);
        }
    }
}

__device__ void root_body(const Ctx& m, int w, int t)
{
    if (w >= 2) return;
    int d = w * 256 + t;
    int u = m.inv_g[0];
    size_t ub = (size_t)u * 1536;
    float iv = m.iou_pre[ub + d]        + m.iou_h[d];
    float ov = m.iou_pre[ub + 512 + d]  + m.iou_h[512 + d];
    float uv = m.iou_pre[ub + 1024 + d] + m.iou_h[1024 + d];
    float fxn = m.fx_pre[(size_t)u * 512 + d];
    float csum = 0.f;
#pragma unroll
    for (int k = 0; k < 4; ++k) {
        int gc = m.children[k];
        float f = sigm(m.fpre[(size_t)k * 512 + d] + fxn);
        csum = fmaf(f, m.c_all[(size_t)gc * 512 + d], csum);
    }
    float cc = sigm(iv) * tanhf(uv) + csum;
    float hh = sigm(ov) * tanhf(cc);
    m.c_all[d] = cc;
    m.h_all[d] = hh;
}

__device__ void level_gemm(const Ctx& m, int l, int nb)
{
    const int E = d_STARTS[l + 1] - d_STARTS[l];
    const int langs = m.cnt[1 + l];
    GSet s0 = m.lv0; s0.nL = langs;     s0.M = E;
    GSet s1 = m.lv1; s1.nL = langs * 4; s1.M = E * 4;
    const int gx = (E * 4 + 127) / 128 + 1;
    for (int f = blockIdx.x; f < gx * 16; f += nb) {
        int ty = f & 15, tx = f >> 4;
        if (ty < 12) gemm_tile(s0, tx, ty * 128);
        else         gemm_tile(s1, tx, (ty - 12) * 128);
    }
}

// ================= persistent TAIL: levels 3..0 + root, 48 blocks, 7 barriers =================
__global__ __launch_bounds__(512, 4)
void tail_mega(Ctx m)
{
    const int nb = gridDim.x;                 // 48
    const int w = blockIdx.x * 2 + (threadIdx.x >> 8);
    const int t = threadIdx.x & 255;
    const int nw = nb * 2;
    int ph = 0;
#pragma unroll 1
    for (int l = 3; l >= 1; --l) {
        level_gemm(m, l, nb);
        gbar(m.sync + ph, nb); ++ph;
        combine_body(m, l, w, t, nw);
        gbar(m.sync + ph, nb); ++ph;
    }
    level_gemm(m, 0, nb);
    gbar(m.sync + ph, nb);
    root_body(m, w, t);
}

// ================= standalone combine+gather (levels 5,4; r8 verified) =================
__global__ __launch_bounds__(256)
void combine_gather(int sPar, int sLvl, Ctx m)
{
    int ip = blockIdx.x;
    int p = m.lvlPerm[sPar + ip];
    int t = threadIdx.x;
    int d0 = t * 2;
    float hsum[2] = {0.f, 0.f};
#pragma unroll
    for (int k = 0; k < 4; ++k) {
        int cnode = m.children[p * 4 + k];
        int j = m.lvlInv[cnode] - sLvl;
        int u = m.inv_g[cnode];
        size_t ub = (size_t)u * 1536;
        size_t jb = (size_t)j * 1536;
#pragma unroll
        for (int e = 0; e < 2; ++e) {
            int d = d0 + e;
            float iv = m.iou_pre[ub + d]        + m.iou_h[jb + d];
            float ov = m.iou_pre[ub + 512 + d]  + m.iou_h[jb + 512 + d];
            float uv = m.iou_pre[ub + 1024 + d] + m.iou_h[jb + 1024 + d];
            float fxn = m.fx_pre[(size_t)u * 512 + d];
            float csum = 0.f;
#pragma unroll
            for (int k2 = 0; k2 < 4; ++k2) {
                int gc = m.children[cnode * 4 + k2];
                float f = sigm(m.fpre[((size_t)(j * 4 + k2)) * 512 + d] + fxn);
                csum = fmaf(f, m.c_all[(size_t)gc * 512 + d], csum);
            }
            float cc = sigm(iv) * tanhf(uv) + csum;
            float hh = sigm(ov) * tanhf(cc);
            m.c_all[(size_t)cnode * 512 + d] = cc;
            m.h_all[(size_t)cnode * 512 + d] = hh;
            hsum[e] += hh;
            _Float16 hf = (_Float16)hh;
            size_t o = ((size_t)(ip * 4 + k)) * 512 + d;
            m.ch_h[o] = hf;
            m.ch_l[o] = (_Float16)((hh - (float)hf) * 2048.0f);
        }
    }
#pragma unroll
    for (int e = 0; e < 2; ++e) {
        _Float16 sh = (_Float16)hsum[e];
        m.hs_h[(size_t)ip * 512 + d0 + e] = sh;
        m.hs_l[(size_t)ip * 512 + d0 + e] = (_Float16)((hsum[e] - (float)sh) * 2048.0f);
    }
}

// ================= leaves + gather(level 5) (r8 verified) =================
__global__ __launch_bounds__(256)
void leaf_gather(Ctx m)
{
    int ip = blockIdx.x;
    int p = m.lvlPerm[341 + ip];
    int t = threadIdx.x;
    int d0 = t * 2;
    int nLg = m.cnt[0];
    float hsum[2] = {0.f, 0.f};
#pragma unroll
    for (int k = 0; k < 4; ++k) {
        int cnode = m.children[p * 4 + k];
        int u = m.inv_g[cnode];
        const float* bh = (u < nLg) ? m.b_iouh_l : m.b_iouh_v;
        size_t ub = (size_t)u * 1536;
#pragma unroll
        for (int e = 0; e < 2; ++e) {
            int d = d0 + e;
            float iv = m.iou_pre[ub + d]        + bh[d];
            float ov = m.iou_pre[ub + 512 + d]  + bh[512 + d];
            float uv = m.iou_pre[ub + 1024 + d] + bh[1024 + d];
            float cc = sigm(iv) * tanhf(uv);
            float hh = sigm(ov) * tanhf(cc);
            m.c_all[(size_t)cnode * 512 + d] = cc;
            m.h_all[(size_t)cnode * 512 + d] = hh;
            hsum[e] += hh;
            _Float16 hf = (_Float16)hh;
            size_t o = ((size_t)(ip * 4 + k)) * 512 + d;
            m.ch_h[o] = hf;
            m.ch_l[o] = (_Float16)((hh - (float)hf) * 2048.0f);
        }
    }
#pragma unroll
    for (int e = 0; e < 2; ++e) {
        _Float16 sh = (_Float16)hsum[e];
        m.hs_h[(size_t)ip * 512 + d0 + e] = sh;
        m.hs_l[(size_t)ip * 512 + d0 + e] = (_Float16)((hsum[e] - (float)sh) * 2048.0f);
    }
}

// ================= fused: x -> fp16 hi/lo split + type-selector logits =================
__global__ __launch_bounds__(256)
void cast_x_sel(const float* __restrict__ x, const float* __restrict__ Wt,
                const float* __restrict__ bt,
                _Float16* __restrict__ hi, _Float16* __restrict__ lo,
                int* __restrict__ sel)
{
    __shared__ float s0[256], s1[256];
    int t = threadIdx.x;
    int row = blockIdx.x * 2 + (t >> 7);
    int c0 = (t & 127) * 4;
    float p0 = 0.f, p1 = 0.f;
    if (row < N_NODES) {
        size_t off = (size_t)row * 512 + c0;
        float4 v = *(const float4*)(x + off);
        float vv[4] = {v.x, v.y, v.z, v.w};
        union { _Float16 h[4]; ushort4 u; } H, L;
#pragma unroll
        for (int i = 0; i < 4; ++i) {
            _Float16 h = (_Float16)vv[i];
            H.h[i] = h;
            L.h[i] = (_Float16)((vv[i] - (float)h) * 2048.0f);
            p0 = fmaf(vv[i], Wt[(c0 + i) * 2], p0);
            p1 = fmaf(vv[i], Wt[(c0 + i) * 2 + 1], p1);
        }
        *(ushort4*)(hi + off) = H.u;
        *(ushort4*)(lo + off) = L.u;
    }
    s0[t] = p0; s1[t] = p1;
    __syncthreads();
    for (int st = 64; st > 0; st >>= 1) {
        if ((t & 127) < st) { s0[t] += s0[t + st]; s1[t] += s1[t + st]; }
        __syncthreads();
    }
    if ((t & 127) == 0 && row < N_NODES)
        sel[row] = (s0[t] + bt[0] >= s1[t] + bt[1]) ? 1 : 0;
}

// ================= prep: weight transpose+split (0..1535) | partition (1536..1542) =================
struct WtArgs {
    const float* src[8];
    _Float16* dsth[8];
    _Float16* dstl[8];
    int nout[8];
};

__global__ __launch_bounds__(256)
void prep(WtArgs a, const int* __restrict__ sel, int* __restrict__ perm_g,
          int* __restrict__ inv_g, int* __restrict__ lvlPerm,
          int* __restrict__ lvlInv, int* __restrict__ cnt)
{
    if (blockIdx.x < 1536) {
        int idx = blockIdx.x;
        int mi = idx / 192;
        int r = idx % 192;
        int n0 = (r >> 3) * 64;
        int k0 = (r & 7) * 64;
        int Nout = a.nout[mi];
        if (n0 >= Nout) return;
        const float* W = a.src[mi];
        _Float16* TH = a.dsth[mi];
        _Float16* TL = a.dstl[mi];
        __shared__ float tbuf[64][65];
        int tx = threadIdx.x & 63, ty = threadIdx.x >> 6;
#pragma unroll
        for (int rr = ty; rr < 64; rr += 4)
            tbuf[rr][tx] = W[(size_t)(k0 + rr) * Nout + n0 + tx];
        __syncthreads();
#pragma unroll
        for (int rr = ty; rr < 64; rr += 4) {
            float v = tbuf[tx][rr];
            _Float16 h = (_Float16)v;
            TH[(size_t)(n0 + rr) * 512 + k0 + tx] = h;
            TL[(size_t)(n0 + rr) * 512 + k0 + tx] = (_Float16)((v - (float)h) * 2048.0f);
        }
    } else {
        __shared__ int ps[256];
        int b = blockIdx.x - 1536;
        int s, e;
        if (b == 0) { s = 0; e = N_NODES; }
        else { s = d_STARTS[b - 1]; e = d_STARTS[b]; }
        int E = e - s;
        int t = threadIdx.x;
        int chunk = (E + 255) / 256;
        int beg = min(t * chunk, E);
        int end = min(beg + chunk, E);
        int c = 0;
        for (int i = beg; i < end; ++i) c += sel[s + i];
        ps[t] = c;
        __syncthreads();
        for (int off = 1; off < 256; off <<= 1) {
            int other = (t >= off) ? ps[t - off] : 0;
            __syncthreads();
            ps[t] += other;
            __syncthreads();
        }
        int total = ps[255];
        int excl = ps[t] - c;
        int pL = excl;
        int pV = total + (beg - excl);
        for (int i = beg; i < end; ++i) {
            int node = s + i;
            int pos = sel[node] ? pL++ : pV++;
            int slot = s + pos;
            if (b == 0) { perm_g[slot] = node; inv_g[node] = slot; }
            else { lvlPerm[slot] = node; lvlInv[node] = slot; }
        }
        if (t == 0) cnt[b] = total;
    }
}

extern "C" void kernel_launch(void* const* d_in, const int* in_sizes, int n_in,
                              void* d_out, int out_size, void* d_ws, size_t ws_size,
                              hipStream_t stream)
{
    const float* x        = (const float*)d_in[0];
    const int*   children = (const int*)  d_in[1];
    const float* W_ioux_v = (const float*)d_in[2];
    const float* b_ioux_v = (const float*)d_in[3];
    const float* W_iouh_v = (const float*)d_in[4];
    const float* b_iouh_v = (const float*)d_in[5];
    const float* W_fx_v   = (const float*)d_in[6];
    const float* b_fx_v   = (const float*)d_in[7];
    const float* W_fh_v   = (const float*)d_in[8];
    const float* b_fh_v   = (const float*)d_in[9];
    const float* W_ioux_l = (const float*)d_in[10];
    const float* b_ioux_l = (const float*)d_in[11];
    const float* W_iouh_l = (const float*)d_in[12];
    const float* b_iouh_l = (const float*)d_in[13];
    const float* W_fx_l   = (const float*)d_in[14];
    const float* b_fx_l   = (const float*)d_in[15];
    const float* W_fh_l   = (const float*)d_in[16];
    const float* b_fh_l   = (const float*)d_in[17];
    const float* W_type   = (const float*)d_in[18];
    const float* b_type   = (const float*)d_in[19];
    float* h_all = (float*)d_out;

    // ---- workspace carve-up ----
    float* p = (float*)d_ws;
    float* iou_pre = p; p += (size_t)N_NODES * 1536;
    float* fx_pre  = p; p += (size_t)N_NODES * 512;
    float* c_all   = p; p += (size_t)N_NODES * 512;
    float* iou_h   = p; p += (size_t)1024 * 1536;
    float* fpre    = p; p += (size_t)4096 * 512;
    int* sel     = (int*)p; p += 6144;
    int* perm_g  = (int*)p; p += 6144;
    int* inv_g   = (int*)p; p += 6144;
    int* lvlPerm = (int*)p; p += 2048;
    int* lvlInv  = (int*)p; p += 2048;
    int* cnt     = (int*)p; p += 64;
    int* gsync   = (int*)p; p += 64;
    _Float16* q = (_Float16*)p;
    _Float16* xh   = q; q += (size_t)N_NODES * 512;
    _Float16* xl   = q; q += (size_t)N_NODES * 512;
    _Float16* hs_h = q; q += (size_t)1024 * 512;
    _Float16* hs_l = q; q += (size_t)1024 * 512;
    _Float16* ch_h = q; q += (size_t)4096 * 512;
    _Float16* ch_l = q; q += (size_t)4096 * 512;
    _Float16* wt_ioux_vh = q; q += (size_t)1536 * 512;
    _Float16* wt_ioux_vl = q; q += (size_t)1536 * 512;
    _Float16* wt_ioux_lh = q; q += (size_t)1536 * 512;
    _Float16* wt_ioux_ll = q; q += (size_t)1536 * 512;
    _Float16* wt_iouh_vh = q; q += (size_t)1536 * 512;
    _Float16* wt_iouh_vl = q; q += (size_t)1536 * 512;
    _Float16* wt_iouh_lh = q; q += (size_t)1536 * 512;
    _Float16* wt_iouh_ll = q; q += (size_t)1536 * 512;
    _Float16* wt_fx_vh   = q; q += (size_t)512 * 512;
    _Float16* wt_fx_vl   = q; q += (size_t)512 * 512;
    _Float16* wt_fx_lh   = q; q += (size_t)512 * 512;
    _Float16* wt_fx_ll   = q; q += (size_t)512 * 512;
    _Float16* wt_fh_vh   = q; q += (size_t)512 * 512;
    _Float16* wt_fh_vl   = q; q += (size_t)512 * 512;
    _Float16* wt_fh_lh   = q; q += (size_t)512 * 512;
    _Float16* wt_fh_ll   = q; q += (size_t)512 * 512;

    hipMemsetAsync(gsync, 0, 64 * sizeof(int), stream);

    cast_x_sel<<<(N_NODES + 1) / 2, 256, 0, stream>>>(x, W_type, b_type, xh, xl, sel);

    WtArgs wa;
    wa.src[0] = W_ioux_v; wa.dsth[0] = wt_ioux_vh; wa.dstl[0] = wt_ioux_vl; wa.nout[0] = 1536;
    wa.src[1] = W_ioux_l; wa.dsth[1] = wt_ioux_lh; wa.dstl[1] = wt_ioux_ll; wa.nout[1] = 1536;
    wa.src[2] = W_iouh_v; wa.dsth[2] = wt_iouh_vh; wa.dstl[2] = wt_iouh_vl; wa.nout[2] = 1536;
    wa.src[3] = W_iouh_l; wa.dsth[3] = wt_iouh_lh; wa.dstl[3] = wt_iouh_ll; wa.nout[3] = 1536;
    wa.src[4] = W_fx_v;   wa.dsth[4] = wt_fx_vh;   wa.dstl[4] = wt_fx_vl;   wa.nout[4] = 512;
    wa.src[5] = W_fx_l;   wa.dsth[5] = wt_fx_lh;   wa.dstl[5] = wt_fx_ll;   wa.nout[5] = 512;
    wa.src[6] = W_fh_v;   wa.dsth[6] = wt_fh_vh;   wa.dstl[6] = wt_fh_vl;   wa.nout[6] = 512;
    wa.src[7] = W_fh_l;   wa.dsth[7] = wt_fh_lh;   wa.dstl[7] = wt_fh_ll;   wa.nout[7] = 512;
    prep<<<1543, 256, 0, stream>>>(wa, sel, perm_g, inv_g, lvlPerm, lvlInv, cnt);

    // ---- shared context ----
    Ctx m{};
    m.lv0 = GSet{hs_h, hs_l, wt_iouh_lh, wt_iouh_ll, wt_iouh_vh, wt_iouh_vl,
                 b_iouh_l, b_iouh_v, iou_h, nullptr, 0, 0, 1536};
    m.lv1 = GSet{ch_h, ch_l, wt_fh_lh, wt_fh_ll, wt_fh_vh, wt_fh_vl,
                 b_fh_l, b_fh_v, fpre, nullptr, 0, 0, 512};
    m.cnt = cnt;
    m.iou_pre = iou_pre; m.fx_pre = fx_pre;
    m.iou_h = iou_h; m.fpre = fpre; m.c_all = c_all; m.h_all = h_all;
    m.children = children; m.lvlPerm = lvlPerm; m.lvlInv = lvlInv; m.inv_g = inv_g;
    m.b_iouh_v = b_iouh_v; m.b_iouh_l = b_iouh_l;
    m.hs_h = hs_h; m.hs_l = hs_l; m.ch_h = ch_h; m.ch_l = ch_l;
    m.sync = gsync;

    // ---- precompute GEMMs (ioux 12 col-tiles + fx 4 col-tiles) ----
    {
        GP g{};
        g.s0 = GSet{xh, xl, wt_ioux_lh, wt_ioux_ll, wt_ioux_vh, wt_ioux_vl,
                    b_ioux_l, b_ioux_v, iou_pre, perm_g, 0, N_NODES, 1536};
        g.s1 = GSet{xh, xl, wt_fx_lh, wt_fx_ll, wt_fx_vh, wt_fx_vl,
                    b_fx_l, b_fx_v, fx_pre, perm_g, 0, N_NODES, 512};
        g.cntPtr = cnt; g.cntScale0 = 1; g.cntScale1 = 1; g.yT0 = 12;
        gemm_pair<<<dim3(44, 16), 512, 0, stream>>>(g);
    }

    // ---- leaves + gather(level 5) ----
    leaf_gather<<<1024, 256, 0, stream>>>(m);

    // ---- levels 5 and 4 (big): separate launches ----
    static const int STARTS[8] = {0, 1, 5, 21, 85, 341, 1365, 5461};
    for (int l = 5; l >= 4; --l) {
        int s = STARTS[l];
        int E = STARTS[l + 1] - s;
        GP g{};
        g.s0 = m.lv0; g.s0.M = E;
        g.s1 = m.lv1; g.s1.M = E * 4;
        g.cntPtr = cnt + 1 + l; g.cntScale0 = 1; g.cntScale1 = 4; g.yT0 = 12;
        int gx = (E * 4 + 127) / 128 + 1;
        gemm_pair<<<dim3(gx, 16), 512, 0, stream>>>(g);
        combine_gather<<<STARTS[l] - STARTS[l - 1], 256, 0, stream>>>(STARTS[l - 1], s, m);
    }

    // ---- persistent tail: levels 3..0 + root (one launch, 7 internal barriers) ----
    tail_mega<<<48, 512, 0, stream>>>(m);
}